// Round 7
// baseline (163.165 us; speedup 1.0000x reference)
//
#include <hip/hip_runtime.h>

#define NROWS 4096
#define NCOLS 4096
#define TAU 0.95f
#define MARGIN 1.0f
#define LN2F 0.6931471805599453f

// 2048 blocks; role = blockIdx&1 (interleaved for co-resident phase mixing).
// Even: logsum over 4 rows (wave per row). Odd: norm over 4 rows (wave per
// row). NO LDS, NO barriers anywhere; all loads are immediate-consume in
// independent iterations so the compiler software-pipelines them (R5
// post-mortem: barrier-spanning liveness + reg-minimizing allocator serialized
// every load; warm runs proved it's latency, not bandwidth).
__global__ __launch_bounds__(256) void fused_kernel(
    const float* __restrict__ cut_y, const int* __restrict__ cut_label,
    float* __restrict__ norm_out, float* __restrict__ logsum_out) {
  const int wid = threadIdx.x >> 6;
  const int lane = threadIdx.x & 63;
  const int row = (blockIdx.x >> 1) * 4 + wid;

  if ((blockIdx.x & 1) == 0) {
    // ---- logsum_b = sum log(y): fully-coalesced float4 stream ----
    const float4* Yp = (const float4*)(cut_y + (size_t)row * NCOLS);
    float s0 = 0.f, s1 = 0.f, s2 = 0.f, s3 = 0.f;
#define LOG4(V) (__log2f((V).x) + __log2f((V).y) + __log2f((V).z) + __log2f((V).w))
#pragma unroll
    for (int i = 0; i < 4; ++i) {
      const float4 a = Yp[lane + 64 * (4 * i + 0)];
      const float4 b = Yp[lane + 64 * (4 * i + 1)];
      const float4 c = Yp[lane + 64 * (4 * i + 2)];
      const float4 d = Yp[lane + 64 * (4 * i + 3)];
      s0 += LOG4(a);
      s1 += LOG4(b);
      s2 += LOG4(c);
      s3 += LOG4(d);
    }
#undef LOG4
    float s = (s0 + s1) + (s2 + s3);
#pragma unroll
    for (int off = 32; off > 0; off >>= 1) s += __shfl_down(s, off, 64);
    if (lane == 0) logsum_out[row] = s * LN2F;
  } else {
    // ---- norm_b = sum exp2(c*C2/(k+T)): lane owns 64 contiguous labels ----
    const int4* Lp = (const int4*)(cut_label + (size_t)row * NCOLS) + lane * 16;
    unsigned mlo = 0u, mhi = 0u;
#pragma unroll
    for (int i = 0; i < 4; ++i) {
      const int4 a = Lp[4 * i + 0];
      const int4 b = Lp[4 * i + 1];
      const int4 c = Lp[4 * i + 2];
      const int4 d = Lp[4 * i + 3];
      const unsigned na = (unsigned)a.x | ((unsigned)a.y << 1) |
                          ((unsigned)a.z << 2) | ((unsigned)a.w << 3);
      const unsigned nb = (unsigned)b.x | ((unsigned)b.y << 1) |
                          ((unsigned)b.z << 2) | ((unsigned)b.w << 3);
      const unsigned nc = (unsigned)c.x | ((unsigned)c.y << 1) |
                          ((unsigned)c.z << 2) | ((unsigned)c.w << 3);
      const unsigned nd = (unsigned)d.x | ((unsigned)d.y << 1) |
                          ((unsigned)d.z << 2) | ((unsigned)d.w << 3);
      const unsigned group = na | (nb << 4) | (nc << 8) | (nd << 12);
      if (i < 2)
        mlo |= group << (16 * i);
      else
        mhi |= group << (16 * (i - 2));
    }
    const int cnt = __popc(mlo) + __popc(mhi);

    // Wave-inclusive scan of per-lane 1-counts (shfl only).
    int x = cnt;
#pragma unroll
    for (int off = 1; off < 64; off <<= 1) {
      const int v = __shfl_up(x, off, 64);
      if (lane >= off) x += v;
    }
    const int Ttot = __shfl(x, 63, 64);
    int c = x - cnt;  // exclusive prefix for this lane's 64 elements

    const float Tf = (float)Ttot;
    const float C2 = 2.0f / (TAU * LN2F);
    const float kb = (float)(lane * 64 + 1) + Tf;  // k+T for j=0
    float acc0 = 0.f, acc1 = 0.f;
#pragma unroll
    for (int j = 0; j < 64; ++j) {  // fully unrolled; w/shift are constants
      const unsigned w = (j < 32) ? mlo : mhi;
      c += (int)((w >> (j & 31)) & 1u);
      // c==0 -> 0/den = 0 -> exp2(0)=1, matching the reference's where().
      const float term =
          __builtin_amdgcn_exp2f(__fdividef((float)c * C2, kb + (float)j));
      if (j & 1)
        acc1 += term;
      else
        acc0 += term;
    }
    float norm = acc0 + acc1;
#pragma unroll
    for (int off = 32; off > 0; off >>= 1) norm += __shfl_down(norm, off, 64);
    if (lane == 0) norm_out[row] = norm;
  }
}

// Single block: combine per-row (logsum, norm) + rerank hinge loss.
__global__ __launch_bounds__(256) void finish_kernel(
    const float* __restrict__ norms, const float* __restrict__ logsums,
    const float* __restrict__ rerank_y, float* __restrict__ out) {
  const int t = threadIdx.x;
  const int lane = t & 63, wid = t >> 6;

  float acc = 0.f;
  const float4* n4 = (const float4*)norms;    // 4096 floats = 1024 float4
  const float4* l4 = (const float4*)logsums;
#pragma unroll
  for (int i = 0; i < 4; ++i) {
    const float4 n = n4[t + 256 * i];
    const float4 l = l4[t + 256 * i];
    acc += __fdividef(l.x, n.x) + __fdividef(l.y, n.y) +
           __fdividef(l.z, n.z) + __fdividef(l.w, n.w);
  }
  acc *= -(1.0f / (float)NROWS);

  float racc = 0.f;
  const float4* y4 = (const float4*)rerank_y;  // 8192 floats; float4 = 2 pairs
#pragma unroll
  for (int i = 0; i < 8; ++i) {
    const float4 v = y4[t + 256 * i];
    racc += fmaxf(0.f, MARGIN - (v.x - v.y));
    racc += fmaxf(0.f, MARGIN - (v.z - v.w));
  }
  acc += racc * (1.0f / 4096.0f);

#pragma unroll
  for (int off = 32; off > 0; off >>= 1) acc += __shfl_down(acc, off, 64);
  __shared__ float ws[4];
  if (lane == 0) ws[wid] = acc;
  __syncthreads();
  if (t == 0) out[0] = (ws[0] + ws[1]) + (ws[2] + ws[3]);
}

extern "C" void kernel_launch(void* const* d_in, const int* in_sizes, int n_in,
                              void* d_out, int out_size, void* d_ws, size_t ws_size,
                              hipStream_t stream) {
  const float* rerank_y = (const float*)d_in[0];   // (8192, 1) f32
  const float* cut_y = (const float*)d_in[1];      // (4096, 4096, 1) f32
  // d_in[2] = rerank_label, unused by the reference loss
  const int* cut_label = (const int*)d_in[3];      // (4096, 4096) i32
  float* out = (float*)d_out;                      // scalar f32
  float* norms = (float*)d_ws;                     // 4096 f32
  float* logsums = (float*)d_ws + NROWS;           // 4096 f32

  fused_kernel<<<2 * (NROWS / 4), 256, 0, stream>>>(cut_y, cut_label, norms,
                                                    logsums);
  finish_kernel<<<1, 256, 0, stream>>>(norms, logsums, rerank_y, out);
}

// Round 8
// 157.259 us; speedup vs baseline: 1.0376x; 1.0376x over previous
//
#include <hip/hip_runtime.h>

#define NROWS 4096
#define NCOLS 4096
#define TAU 0.95f
#define MARGIN 1.0f
#define LN2F 0.6931471805599453f

// Barrier-free per-row norm computation. Inputs: packed label nibbles
// (mlo/mhi: nibble s = labels of columns s*256+lane*4 .. +3) and per-segment
// popcounts packed as 8 u32s of 2 halfwords (p[i] = cnt(seg 2i) | cnt(seg
// 2i+1)<<16). SWAR halfword lane-scan is exact (max prefix 256 < 65536).
__device__ __forceinline__ void norm_row(unsigned mlo, unsigned mhi,
                                         const unsigned* __restrict__ p,
                                         int lane, float* __restrict__ dst) {
  unsigned h[8];
#pragma unroll
  for (int i = 0; i < 8; ++i) h[i] = p[i];
  // Inclusive lane-scan of 16 per-segment counts (6 shfl steps x 8 regs).
#pragma unroll
  for (int off = 1; off < 64; off <<= 1) {
    unsigned v[8];
#pragma unroll
    for (int i = 0; i < 8; ++i) v[i] = __shfl_up(h[i], off, 64);
    if (lane >= off) {
#pragma unroll
      for (int i = 0; i < 8; ++i) h[i] += v[i];
    }
  }
  unsigned ex[8], tot[8];
#pragma unroll
  for (int i = 0; i < 8; ++i) ex[i] = h[i] - p[i];  // exclusive lane prefix
#pragma unroll
  for (int i = 0; i < 8; ++i) tot[i] = __shfl(h[i], 63, 64);  // segment totals

  // Row total T: sum 16 halfwords (per-halfword sums <= 2048, no overflow).
  const unsigned tsum = ((tot[0] + tot[1]) + (tot[2] + tot[3])) +
                        ((tot[4] + tot[5]) + (tot[6] + tot[7]));
  const float Tf = (float)((tsum & 0xFFFFu) + (tsum >> 16));

  const float C2 = 2.0f / (TAU * LN2F);
  float acc0 = 0.f, acc1 = 0.f;
  unsigned run = 0;  // prefix of segment totals, updated in ascending s
#pragma unroll
  for (int s = 0; s < 16; ++s) {
    const unsigned nib = ((s < 8) ? (mlo >> (4 * s)) : (mhi >> (4 * (s - 8)))) & 0xFu;
    const unsigned exl = (ex[s >> 1] >> (16 * (s & 1))) & 0xFFFFu;
    int c = (int)(run + exl);
    const float kb = (float)(s * 256 + lane * 4 + 1) + Tf;  // k+T at j=0
    c += (int)(nib & 1u);
    acc0 += __builtin_amdgcn_exp2f(__fdividef((float)c * C2, kb));
    c += (int)((nib >> 1) & 1u);
    acc1 += __builtin_amdgcn_exp2f(__fdividef((float)c * C2, kb + 1.0f));
    c += (int)((nib >> 2) & 1u);
    acc0 += __builtin_amdgcn_exp2f(__fdividef((float)c * C2, kb + 2.0f));
    c += (int)((nib >> 3) & 1u);
    acc1 += __builtin_amdgcn_exp2f(__fdividef((float)c * C2, kb + 3.0f));
    run += (tot[s >> 1] >> (16 * (s & 1))) & 0xFFFFu;
  }
  float norm = acc0 + acc1;
#pragma unroll
  for (int off = 32; off > 0; off >>= 1) norm += __shfl_down(norm, off, 64);
  if (lane == 0) *dst = norm;
}

__device__ __forceinline__ void pack_row(const int4* __restrict__ buf,
                                         unsigned& mlo, unsigned& mhi,
                                         unsigned* __restrict__ p) {
  unsigned nib[16];
#pragma unroll
  for (int s = 0; s < 16; ++s)
    nib[s] = (unsigned)buf[s].x | ((unsigned)buf[s].y << 1) |
             ((unsigned)buf[s].z << 2) | ((unsigned)buf[s].w << 3);
  mlo = 0u;
  mhi = 0u;
#pragma unroll
  for (int s = 0; s < 8; ++s) mlo |= nib[s] << (4 * s);
#pragma unroll
  for (int s = 8; s < 16; ++s) mhi |= nib[s] << (4 * (s - 8));
#pragma unroll
  for (int i = 0; i < 8; ++i)
    p[i] = (unsigned)__popc(nib[2 * i]) | ((unsigned)__popc(nib[2 * i + 1]) << 16);
}

// 1024 persistent blocks; role alternates every 8 blocks (XCD-balanced).
// 2 rows per wave, software-pipelined: next row's coalesced loads are issued
// BEFORE the current row's long compute; zero LDS / zero barriers so no
// vmcnt(0) drain ever interrupts the pipeline (R3/R5 vs R7 evidence:
// coalesced=44us vs uncoalesced=57us; warm==cold -> latency-bound).
__global__ __launch_bounds__(256) void fused_kernel(
    const float* __restrict__ cut_y, const int* __restrict__ cut_label,
    float* __restrict__ norm_out, float* __restrict__ logsum_out) {
  const int g = blockIdx.x;                    // [0,1024)
  const int role = (g >> 3) & 1;               // alternates per XCD-stripe
  const int idx = (g & 7) | ((g >> 4) << 3);   // [0,512) within role
  const int wid = threadIdx.x >> 6;
  const int lane = threadIdx.x & 63;
  const int r0 = (idx * 4 + wid) * 2;          // this wave's rows: r0, r0+1

  if (role == 0) {
    // ---- logsum: half-row (8 float4) double buffer, coalesced ----
    const float4* Y0 = (const float4*)(cut_y + (size_t)r0 * NCOLS) + lane;
    const float4* Y1 = (const float4*)(cut_y + (size_t)(r0 + 1) * NCOLS) + lane;
    float4 a[8], b[8];
#pragma unroll
    for (int s = 0; s < 8; ++s) a[s] = Y0[s * 64];
#pragma unroll
    for (int s = 0; s < 8; ++s) b[s] = Y0[(s + 8) * 64];
    float t0 = 0.f, t1 = 0.f, t2 = 0.f, t3 = 0.f;
#pragma unroll
    for (int s = 0; s < 8; ++s) {
      t0 += __log2f(a[s].x); t1 += __log2f(a[s].y);
      t2 += __log2f(a[s].z); t3 += __log2f(a[s].w);
    }
#pragma unroll
    for (int s = 0; s < 8; ++s) a[s] = Y1[s * 64];  // refill while b consumed
#pragma unroll
    for (int s = 0; s < 8; ++s) {
      t0 += __log2f(b[s].x); t1 += __log2f(b[s].y);
      t2 += __log2f(b[s].z); t3 += __log2f(b[s].w);
    }
#pragma unroll
    for (int s = 0; s < 8; ++s) b[s] = Y1[(s + 8) * 64];
    float srow = (t0 + t1) + (t2 + t3);
#pragma unroll
    for (int off = 32; off > 0; off >>= 1) srow += __shfl_down(srow, off, 64);
    if (lane == 0) logsum_out[r0] = srow * LN2F;
    t0 = t1 = t2 = t3 = 0.f;
#pragma unroll
    for (int s = 0; s < 8; ++s) {
      t0 += __log2f(a[s].x); t1 += __log2f(a[s].y);
      t2 += __log2f(a[s].z); t3 += __log2f(a[s].w);
    }
#pragma unroll
    for (int s = 0; s < 8; ++s) {
      t0 += __log2f(b[s].x); t1 += __log2f(b[s].y);
      t2 += __log2f(b[s].z); t3 += __log2f(b[s].w);
    }
    srow = (t0 + t1) + (t2 + t3);
#pragma unroll
    for (int off = 32; off > 0; off >>= 1) srow += __shfl_down(srow, off, 64);
    if (lane == 0) logsum_out[r0 + 1] = srow * LN2F;
  } else {
    // ---- norm: full-row prefetch pipeline, coalesced int4 ----
    const int4* L0 = (const int4*)(cut_label + (size_t)r0 * NCOLS) + lane;
    const int4* L1 = (const int4*)(cut_label + (size_t)(r0 + 1) * NCOLS) + lane;
    int4 buf[16];
#pragma unroll
    for (int s = 0; s < 16; ++s) buf[s] = L0[s * 64];

    unsigned mlo, mhi, p[8];
    pack_row(buf, mlo, mhi, p);  // consumes row r0; buf now dead
#pragma unroll
    for (int s = 0; s < 16; ++s) buf[s] = L1[s * 64];  // prefetch row r0+1
    norm_row(mlo, mhi, p, lane, norm_out + r0);        // ~1.3K cy, hides loads

    pack_row(buf, mlo, mhi, p);
    norm_row(mlo, mhi, p, lane, norm_out + r0 + 1);
  }
}

// Single block: combine per-row (logsum, norm) + rerank hinge loss.
__global__ __launch_bounds__(256) void finish_kernel(
    const float* __restrict__ norms, const float* __restrict__ logsums,
    const float* __restrict__ rerank_y, float* __restrict__ out) {
  const int t = threadIdx.x;
  const int lane = t & 63, wid = t >> 6;

  float acc = 0.f;
  const float4* n4 = (const float4*)norms;  // 4096 floats = 1024 float4
  const float4* l4 = (const float4*)logsums;
#pragma unroll
  for (int i = 0; i < 4; ++i) {
    const float4 n = n4[t + 256 * i];
    const float4 l = l4[t + 256 * i];
    acc += __fdividef(l.x, n.x) + __fdividef(l.y, n.y) +
           __fdividef(l.z, n.z) + __fdividef(l.w, n.w);
  }
  acc *= -(1.0f / (float)NROWS);

  float racc = 0.f;
  const float4* y4 = (const float4*)rerank_y;  // 8192 floats; float4 = 2 pairs
#pragma unroll
  for (int i = 0; i < 8; ++i) {
    const float4 v = y4[t + 256 * i];
    racc += fmaxf(0.f, MARGIN - (v.x - v.y));
    racc += fmaxf(0.f, MARGIN - (v.z - v.w));
  }
  acc += racc * (1.0f / 4096.0f);

#pragma unroll
  for (int off = 32; off > 0; off >>= 1) acc += __shfl_down(acc, off, 64);
  __shared__ float ws[4];
  if (lane == 0) ws[wid] = acc;
  __syncthreads();
  if (t == 0) out[0] = (ws[0] + ws[1]) + (ws[2] + ws[3]);
}

extern "C" void kernel_launch(void* const* d_in, const int* in_sizes, int n_in,
                              void* d_out, int out_size, void* d_ws, size_t ws_size,
                              hipStream_t stream) {
  const float* rerank_y = (const float*)d_in[0];   // (8192, 1) f32
  const float* cut_y = (const float*)d_in[1];      // (4096, 4096, 1) f32
  // d_in[2] = rerank_label, unused by the reference loss
  const int* cut_label = (const int*)d_in[3];      // (4096, 4096) i32
  float* out = (float*)d_out;                      // scalar f32
  float* norms = (float*)d_ws;                     // 4096 f32
  float* logsums = (float*)d_ws + NROWS;           // 4096 f32

  fused_kernel<<<1024, 256, 0, stream>>>(cut_y, cut_label, norms, logsums);
  finish_kernel<<<1, 256, 0, stream>>>(norms, logsums, rerank_y, out);
}